// Round 2
// baseline (23393.752 us; speedup 1.0000x reference)
//
#include <hip/hip_runtime.h>
#include <math.h>

#define S_LEN 4096
#define NTAG 20
#define TAG_STOP 19
#define NEGV -10000.0f
#define NWG 16   // workgroups per LSTM direction

// ---------------- workspace layout (bytes) ----------------
// [0,512)        uint flags[128]        (dir0: [0,64), dir1: [64,128)) per-wave step flags
// [512,8704)     float h_buf[2][2][512] (dir, parity, hid)
// [16384, +64MB) float pre[4096][4096]  (pos, row; rows 0..2047 fwd, 2048..4095 bwd)
// then           float hs[2][4096][512]
// then           float feats[4096][20]
// then           u8    bptr[4096*20]

__global__ void init_ctr(unsigned int* flags) {
    if (threadIdx.x < 128) flags[threadIdx.x] = 0u;
}

__device__ __forceinline__ float sigm(float x) { return 1.0f / (1.0f + expf(-x)); }

// ---------------- kernel A: embed gather + input GEMM (fp32) ----------------
__launch_bounds__(256)
__global__ void pre_gemm(const int* __restrict__ sent, const float* __restrict__ embed,
                         const float* __restrict__ wf, const float* __restrict__ wb,
                         const float* __restrict__ bihf, const float* __restrict__ bhhf,
                         const float* __restrict__ bihb, const float* __restrict__ bhhb,
                         float* __restrict__ pre)
{
    __shared__ float As[16][68];
    __shared__ float Bs[16][136];
    __shared__ int   srow[64];
    const int tid = threadIdx.x;
    const int bm = blockIdx.x & 63;     // 64 pos-blocks
    const int bn = blockIdx.x >> 6;     // 32 row-blocks
    const int pos0 = bm * 64, row0 = bn * 128;
    if (tid < 64) srow[tid] = sent[pos0 + tid];
    __syncthreads();

    const int tx = tid & 15, ty = tid >> 4;
    float acc[4][8];
    #pragma unroll
    for (int m = 0; m < 4; ++m)
        #pragma unroll
        for (int n = 0; n < 8; ++n) acc[m][n] = 0.f;

    for (int kt = 0; kt < 1024; kt += 16) {
        {   // A tile: 64 pos x 16 k
            int m = tid >> 2, kc = (tid & 3) * 4;
            const float* src = embed + (size_t)srow[m] * 1024 + kt + kc;
            float4 v = *(const float4*)src;
            As[kc+0][m] = v.x; As[kc+1][m] = v.y; As[kc+2][m] = v.z; As[kc+3][m] = v.w;
        }
        #pragma unroll
        for (int it = 0; it < 2; ++it) {   // B tile: 128 rows x 16 k
            int n = (tid >> 2) + it * 64;
            int kc = (tid & 3) * 4;
            int grow = row0 + n;
            const float* wsrc = (grow < 2048) ? (wf + (size_t)grow * 1024)
                                              : (wb + (size_t)(grow - 2048) * 1024);
            float4 v = *(const float4*)(wsrc + kt + kc);
            Bs[kc+0][n] = v.x; Bs[kc+1][n] = v.y; Bs[kc+2][n] = v.z; Bs[kc+3][n] = v.w;
        }
        __syncthreads();
        #pragma unroll
        for (int kk = 0; kk < 16; ++kk) {
            float a[4], b[8];
            float4 av = *(const float4*)&As[kk][ty * 4];
            a[0] = av.x; a[1] = av.y; a[2] = av.z; a[3] = av.w;
            float4 bv0 = *(const float4*)&Bs[kk][tx * 8];
            float4 bv1 = *(const float4*)&Bs[kk][tx * 8 + 4];
            b[0]=bv0.x; b[1]=bv0.y; b[2]=bv0.z; b[3]=bv0.w;
            b[4]=bv1.x; b[5]=bv1.y; b[6]=bv1.z; b[7]=bv1.w;
            #pragma unroll
            for (int m = 0; m < 4; ++m)
                #pragma unroll
                for (int n = 0; n < 8; ++n) acc[m][n] += a[m] * b[n];
        }
        __syncthreads();
    }
    #pragma unroll
    for (int m = 0; m < 4; ++m) {
        int pos = pos0 + ty * 4 + m;
        #pragma unroll
        for (int n = 0; n < 8; ++n) {
            int grow = row0 + tx * 8 + n;
            float bias = (grow < 2048) ? (bihf[grow] + bhhf[grow])
                                       : (bihb[grow - 2048] + bhhb[grow - 2048]);
            pre[(size_t)pos * 4096 + grow] = acc[m][n] + bias;
        }
    }
}

// ---------------- kernel B: bidirectional LSTM, register-resident W_hh ----------------
// 32 blocks x 256 threads; blocks 0..15 = fwd, 16..31 = bwd. WG owns 32 hidden units
// (128 gate rows). Thread (rg=tid>>4, ks=tid&15): rows rl=8rg..8rg+7 over k in
// [32ks,32ks+32) -> 256 weight floats in regs. Cross-WG h exchange: write-through
// device-coherent atomics (sc0 sc1), per-wave flags, NO cache-flushing fences.
__launch_bounds__(256, 1)
__global__ void lstm_kernel(const float* __restrict__ pre,
                            const float* __restrict__ w_hh_f, const float* __restrict__ w_hh_b,
                            const float* __restrict__ h0, const float* __restrict__ c0,
                            float* __restrict__ hs, float* __restrict__ h_buf,
                            unsigned int* __restrict__ flags)
{
    const int dir = blockIdx.x >> 4;
    const int wg  = blockIdx.x & 15;
    const int tid = threadIdx.x;
    const int rg  = tid >> 4;
    const int ks  = tid & 15;
    const float* w_hh = dir ? w_hh_b : w_hh_f;

    __shared__ float h_lds[2][576];   // double-buffered, padded (+4 per 32)

    // one-time: weights into registers. row rl = rg*8+r -> grow=(rl&3)*512 + wg*32 + (rl>>2)
    float w[8][32];
    #pragma unroll
    for (int r = 0; r < 8; ++r) {
        int rl = rg * 8 + r;
        int grow = (rl & 3) * 512 + wg * 32 + (rl >> 2);
        const float4* src = (const float4*)(w_hh + (size_t)grow * 512 + ks * 32);
        #pragma unroll
        for (int q = 0; q < 8; ++q) {
            float4 v = src[q];
            w[r][q*4+0] = v.x; w[r][q*4+1] = v.y; w[r][q*4+2] = v.z; w[r][q*4+3] = v.w;
        }
    }

    // c-state: ks==0 lane of group rg owns hidden units j = wg*32 + 2rg, +1
    float c_a = 0.f, c_b = 0.f;
    if (ks == 0) {
        c_a = c0[dir * 512 + wg * 32 + 2 * rg];
        c_b = c0[dir * 512 + wg * 32 + 2 * rg + 1];
    }

    unsigned int* my_flags = flags + dir * 64;

    // prefetch pre for step 0: pf[r] = pre row gate=(r&3), unit 2rg+(r>>2)
    float pf[8];
    {
        int p0 = dir ? (S_LEN - 1) : 0;
        if (ks == 0) {
            const float* pb = pre + (size_t)p0 * 4096 + dir * 2048 + wg * 32 + 2 * rg;
            #pragma unroll
            for (int g = 0; g < 4; ++g) {
                float2 v = *(const float2*)(pb + g * 512);
                pf[g] = v.x; pf[4 + g] = v.y;
            }
        }
    }

    // stage h0 into parity 0
    {
        int k = tid;       h_lds[0][k + ((k >> 5) << 2)] = h0[dir * 512 + k];
        k = tid + 256;     h_lds[0][k + ((k >> 5) << 2)] = h0[dir * 512 + k];
    }
    __syncthreads();

    for (int s = 0; s < S_LEN; ++s) {
        const int par = s & 1;
        const int pos = dir ? (S_LEN - 1 - s) : s;

        // gate pre-activations: 256 FMAs per thread over this thread's k-slice
        float acc[8] = {0, 0, 0, 0, 0, 0, 0, 0};
        const float4* hp = (const float4*)&h_lds[par][ks * 36];
        #pragma unroll
        for (int q = 0; q < 8; ++q) {
            float4 h4 = hp[q];
            #pragma unroll
            for (int r = 0; r < 8; ++r)
                acc[r] += w[r][q*4+0] * h4.x + w[r][q*4+1] * h4.y
                        + w[r][q*4+2] * h4.z + w[r][q*4+3] * h4.w;
        }
        if (ks == 0) {
            #pragma unroll
            for (int r = 0; r < 8; ++r) acc[r] += pf[r];
        }
        // butterfly all-reduce over the 16 k-slices (lanes 16rg..16rg+15)
        #pragma unroll
        for (int m = 1; m <= 8; m <<= 1)
            #pragma unroll
            for (int r = 0; r < 8; ++r)
                acc[r] += __shfl_xor(acc[r], m);

        // nonlinearity + device-coherent h store (ks==0 lanes only)
        float hn_a = 0.f, hn_b = 0.f;
        if (ks == 0) {
            float ia = sigm(acc[0]), fa = sigm(acc[1]), ga = tanhf(acc[2]), oa = sigm(acc[3]);
            c_a = fa * c_a + ia * ga;  hn_a = oa * tanhf(c_a);
            float ib = sigm(acc[4]), fb = sigm(acc[5]), gb = tanhf(acc[6]), ob = sigm(acc[7]);
            c_b = fb * c_b + ib * gb;  hn_b = ob * tanhf(c_b);
            float* hb = h_buf + ((dir * 2) + par) * 512 + wg * 32 + 2 * rg;
            __hip_atomic_store(&hb[0], hn_a, __ATOMIC_RELAXED, __HIP_MEMORY_SCOPE_AGENT);
            __hip_atomic_store(&hb[1], hn_b, __ATOMIC_RELAXED, __HIP_MEMORY_SCOPE_AGENT);
        }

        if (s + 1 == S_LEN) {   // last step: no one consumes h; just emit hs and exit
            if (ks == 0) {
                float* hsp = hs + ((size_t)dir * S_LEN + pos) * 512 + wg * 32 + 2 * rg;
                __builtin_nontemporal_store(hn_a, &hsp[0]);
                __builtin_nontemporal_store(hn_b, &hsp[1]);
            }
            break;
        }

        // per-wave: h stores acked at coherent point, then post this wave's flag
        asm volatile("s_waitcnt vmcnt(0)" ::: "memory");
        if ((tid & 63) == 0)
            __hip_atomic_store(&my_flags[wg * 4 + (tid >> 6)], (unsigned)(s + 1),
                               __ATOMIC_RELAXED, __HIP_MEMORY_SCOPE_AGENT);

        // off-critical-path work while peers catch up: hs store + next pre prefetch
        if (ks == 0) {
            float* hsp = hs + ((size_t)dir * S_LEN + pos) * 512 + wg * 32 + 2 * rg;
            __builtin_nontemporal_store(hn_a, &hsp[0]);
            __builtin_nontemporal_store(hn_b, &hsp[1]);
            int pn = dir ? (pos - 1) : (pos + 1);
            const float* pb = pre + (size_t)pn * 4096 + dir * 2048 + wg * 32 + 2 * rg;
            #pragma unroll
            for (int g = 0; g < 4; ++g) {
                float2 v = *(const float2*)(pb + g * 512);
                pf[g] = v.x; pf[4 + g] = v.y;
            }
        }

        // every wave polls all 64 wave-flags of its direction (1 flag per lane)
        {
            unsigned target = (unsigned)(s + 1);
            int idx = tid & 63;
            while (!__all(__hip_atomic_load(&my_flags[idx], __ATOMIC_RELAXED,
                                            __HIP_MEMORY_SCOPE_AGENT) >= target)) {}
        }

        // stage h_s into the other LDS parity (coherent loads, coalesced)
        {
            float* hb = h_buf + ((dir * 2) + par) * 512;
            int k = tid;
            float v0 = __hip_atomic_load(&hb[k], __ATOMIC_RELAXED, __HIP_MEMORY_SCOPE_AGENT);
            h_lds[1 - par][k + ((k >> 5) << 2)] = v0;
            k = tid + 256;
            float v1 = __hip_atomic_load(&hb[k], __ATOMIC_RELAXED, __HIP_MEMORY_SCOPE_AGENT);
            h_lds[1 - par][k + ((k >> 5) << 2)] = v1;
        }
        __syncthreads();   // the single per-step barrier
    }
}

// ---------------- kernel C: feats = concat(hf,hb) @ w_out^T + b_out ----------------
__launch_bounds__(256)
__global__ void feats_kernel(const float* __restrict__ hs, const float* __restrict__ w_out,
                             const float* __restrict__ b_out, float* __restrict__ feats)
{
    const int pos = blockIdx.x;
    const int tid = threadIdx.x;
    __shared__ float hbuf[1024];
    __shared__ float red[160];
    {
        const float* hf = hs + (size_t)pos * 512;
        const float* hb = hs + ((size_t)S_LEN + pos) * 512;
        if (tid < 128) *(float4*)&hbuf[tid * 4]        = *(const float4*)&hf[tid * 4];
        else           *(float4*)&hbuf[512 + (tid-128)*4] = *(const float4*)&hb[(tid - 128) * 4];
    }
    __syncthreads();
    if (tid < 160) {
        int tag = tid >> 3, part = tid & 7;
        const float* wrow = w_out + (size_t)tag * 1024 + part * 128;
        const float* hrow = hbuf + part * 128;
        float sum = 0.f;
        #pragma unroll
        for (int q = 0; q < 32; ++q) {
            float4 a = ((const float4*)hrow)[q];
            float4 b = ((const float4*)wrow)[q];
            sum += a.x*b.x + a.y*b.y + a.z*b.z + a.w*b.w;
        }
        red[tid] = sum;
    }
    __syncthreads();
    if (tid < NTAG) {
        float sum = b_out[tid];
        #pragma unroll
        for (int p = 0; p < 8; ++p) sum += red[tid * 8 + p];
        feats[(size_t)pos * NTAG + tid] = sum;
    }
}

// ---------------- kernel D: Viterbi forward + chunked backtrace ----------------
__launch_bounds__(256)
__global__ void viterbi_kernel(const float* __restrict__ feats, const float* __restrict__ trans,
                               unsigned char* __restrict__ bptr, float* __restrict__ out)
{
    __shared__ float feat_lds[64 * NTAG];
    __shared__ int sh_best;
    __shared__ unsigned char Mmap[8][NTAG];
    __shared__ unsigned char entry_s[8];
    const int tid = threadIdx.x;

    if (tid < 64) {   // wave 0: sequential forward pass
        const int lane = tid;
        const int i = (lane < NTAG) ? lane : (NTAG - 1);
        float trow[NTAG];
        #pragma unroll
        for (int j = 0; j < NTAG; ++j) trow[j] = trans[i * NTAG + j];
        float fv[NTAG];
        #pragma unroll
        for (int j = 0; j < NTAG; ++j) fv[j] = (j == 18) ? 0.f : NEGV;

        for (int blk = 0; blk < 64; ++blk) {
            #pragma unroll
            for (int q = 0; q < 20; ++q)
                feat_lds[q * 64 + lane] = feats[blk * 1280 + q * 64 + lane];
            for (int ss = 0; ss < 64; ++ss) {
                int s = blk * 64 + ss;
                float best = fv[0] + trow[0];
                int bj = 0;
                #pragma unroll
                for (int j = 1; j < NTAG; ++j) {
                    float cand = fv[j] + trow[j];
                    if (cand > best) { best = cand; bj = j; }   // strict >: first-max tie rule
                }
                float fnew = best + feat_lds[ss * NTAG + i];
                if (lane < NTAG) bptr[s * NTAG + lane] = (unsigned char)bj;
                #pragma unroll
                for (int j = 0; j < NTAG; ++j) fv[j] = __shfl(fnew, j);
            }
        }
        if (lane == 0) {
            float best = -1e30f; int bt = 0;
            for (int j = 0; j < NTAG; ++j) {
                float t2 = fv[j] + trans[TAG_STOP * NTAG + j];
                if (t2 > best) { best = t2; bt = j; }
            }
            out[0] = best;
            sh_best = bt;
        }
    }
    __syncthreads();
    // phase 1: per-chunk entry-tag -> chunk-start-tag maps (8 chunks x 20 entries)
    if (tid < 160) {
        int c = tid / NTAG, e = tid % NTAG;
        int tag = e;
        for (int t = (c + 1) * 512 - 1; t >= c * 512; --t) tag = bptr[t * NTAG + tag];
        Mmap[c][e] = (unsigned char)tag;
    }
    __syncthreads();
    // phase 2: serial chain through 8 chunk maps
    if (tid == 0) {
        int e = sh_best;
        entry_s[7] = (unsigned char)e;
        for (int c = 7; c >= 1; --c) { e = Mmap[c][e]; entry_s[c - 1] = (unsigned char)e; }
    }
    __syncthreads();
    // phase 3: re-walk each chunk writing the path
    if (tid < 8) {
        int c = tid;
        int tag = entry_s[c];
        out[1 + (c + 1) * 512 - 1] = (float)tag;
        for (int t = (c + 1) * 512 - 1; t > c * 512; --t) {
            tag = bptr[t * NTAG + tag];
            out[1 + t - 1] = (float)tag;
        }
    }
}

extern "C" void kernel_launch(void* const* d_in, const int* in_sizes, int n_in,
                              void* d_out, int out_size, void* d_ws, size_t ws_size,
                              hipStream_t stream) {
    (void)in_sizes; (void)n_in; (void)out_size; (void)ws_size;
    const int*   sent  = (const int*)d_in[0];
    const float* embed = (const float*)d_in[1];
    const float* wihf  = (const float*)d_in[2];
    const float* whhf  = (const float*)d_in[3];
    const float* bihf  = (const float*)d_in[4];
    const float* bhhf  = (const float*)d_in[5];
    const float* wihb  = (const float*)d_in[6];
    const float* whhb  = (const float*)d_in[7];
    const float* bihb  = (const float*)d_in[8];
    const float* bhhb  = (const float*)d_in[9];
    const float* wout  = (const float*)d_in[10];
    const float* bout  = (const float*)d_in[11];
    const float* trans = (const float*)d_in[12];
    const float* h0    = (const float*)d_in[13];
    const float* c0    = (const float*)d_in[14];

    char* ws = (char*)d_ws;
    unsigned int* flags = (unsigned int*)ws;
    float* h_buf = (float*)(ws + 512);
    float* pre   = (float*)(ws + 16384);
    float* hs    = (float*)(ws + 16384 + (size_t)4096 * 4096 * 4);
    float* feats = (float*)(ws + 16384 + (size_t)4096 * 4096 * 4 + (size_t)2 * 4096 * 512 * 4);
    unsigned char* bptr = (unsigned char*)(feats + (size_t)S_LEN * NTAG);
    float* out = (float*)d_out;

    hipLaunchKernelGGL(init_ctr, dim3(1), dim3(128), 0, stream, flags);
    hipLaunchKernelGGL(pre_gemm, dim3(2048), dim3(256), 0, stream,
                       sent, embed, wihf, wihb, bihf, bhhf, bihb, bhhb, pre);
    hipLaunchKernelGGL(lstm_kernel, dim3(32), dim3(256), 0, stream,
                       pre, whhf, whhb, h0, c0, hs, h_buf, flags);
    hipLaunchKernelGGL(feats_kernel, dim3(S_LEN), dim3(256), 0, stream,
                       hs, wout, bout, feats);
    hipLaunchKernelGGL(viterbi_kernel, dim3(1), dim3(256), 0, stream,
                       feats, trans, bptr, out);
}

// Round 3
// 18928.851 us; speedup vs baseline: 1.2359x; 1.2359x over previous
//
#include <hip/hip_runtime.h>
#include <math.h>

#define S_LEN 4096
#define NTAG 20
#define TAG_STOP 19
#define NEGV -10000.0f
#define NWG 16   // workgroups per LSTM direction

// ---------------- workspace layout (bytes) ----------------
// [0,16384)      ulong ring[2][2][512]  (dir, parity, hid): packed (f32 h | u32 tag)
// [16384, +64MB) float pre[4096][4096]  (pos, row; rows 0..2047 fwd, 2048..4095 bwd)
// then           float hs[2][4096][512]
// then           float feats[4096][20]
// then           u8    bptr[4096*20]
// Poison 0xAAAAAAAA never equals a live tag (1..4096) -> no init kernel needed.

__device__ __forceinline__ float sigm(float x) { return 1.0f / (1.0f + expf(-x)); }

// ---------------- kernel A: embed gather + input GEMM (fp32) ----------------
__launch_bounds__(256)
__global__ void pre_gemm(const int* __restrict__ sent, const float* __restrict__ embed,
                         const float* __restrict__ wf, const float* __restrict__ wb,
                         const float* __restrict__ bihf, const float* __restrict__ bhhf,
                         const float* __restrict__ bihb, const float* __restrict__ bhhb,
                         float* __restrict__ pre)
{
    __shared__ float As[16][68];
    __shared__ float Bs[16][136];
    __shared__ int   srow[64];
    const int tid = threadIdx.x;
    const int bm = blockIdx.x & 63;     // 64 pos-blocks
    const int bn = blockIdx.x >> 6;     // 32 row-blocks
    const int pos0 = bm * 64, row0 = bn * 128;
    if (tid < 64) srow[tid] = sent[pos0 + tid];
    __syncthreads();

    const int tx = tid & 15, ty = tid >> 4;
    float acc[4][8];
    #pragma unroll
    for (int m = 0; m < 4; ++m)
        #pragma unroll
        for (int n = 0; n < 8; ++n) acc[m][n] = 0.f;

    for (int kt = 0; kt < 1024; kt += 16) {
        {   // A tile: 64 pos x 16 k
            int m = tid >> 2, kc = (tid & 3) * 4;
            const float* src = embed + (size_t)srow[m] * 1024 + kt + kc;
            float4 v = *(const float4*)src;
            As[kc+0][m] = v.x; As[kc+1][m] = v.y; As[kc+2][m] = v.z; As[kc+3][m] = v.w;
        }
        #pragma unroll
        for (int it = 0; it < 2; ++it) {   // B tile: 128 rows x 16 k
            int n = (tid >> 2) + it * 64;
            int kc = (tid & 3) * 4;
            int grow = row0 + n;
            const float* wsrc = (grow < 2048) ? (wf + (size_t)grow * 1024)
                                              : (wb + (size_t)(grow - 2048) * 1024);
            float4 v = *(const float4*)(wsrc + kt + kc);
            Bs[kc+0][n] = v.x; Bs[kc+1][n] = v.y; Bs[kc+2][n] = v.z; Bs[kc+3][n] = v.w;
        }
        __syncthreads();
        #pragma unroll
        for (int kk = 0; kk < 16; ++kk) {
            float a[4], b[8];
            float4 av = *(const float4*)&As[kk][ty * 4];
            a[0] = av.x; a[1] = av.y; a[2] = av.z; a[3] = av.w;
            float4 bv0 = *(const float4*)&Bs[kk][tx * 8];
            float4 bv1 = *(const float4*)&Bs[kk][tx * 8 + 4];
            b[0]=bv0.x; b[1]=bv0.y; b[2]=bv0.z; b[3]=bv0.w;
            b[4]=bv1.x; b[5]=bv1.y; b[6]=bv1.z; b[7]=bv1.w;
            #pragma unroll
            for (int m = 0; m < 4; ++m)
                #pragma unroll
                for (int n = 0; n < 8; ++n) acc[m][n] += a[m] * b[n];
        }
        __syncthreads();
    }
    #pragma unroll
    for (int m = 0; m < 4; ++m) {
        int pos = pos0 + ty * 4 + m;
        #pragma unroll
        for (int n = 0; n < 8; ++n) {
            int grow = row0 + tx * 8 + n;
            float bias = (grow < 2048) ? (bihf[grow] + bhhf[grow])
                                       : (bihb[grow - 2048] + bhhb[grow - 2048]);
            pre[(size_t)pos * 4096 + grow] = acc[m][n] + bias;
        }
    }
}

// ---------------- kernel B: bidirectional LSTM, self-validating h ring ----------------
// 32 blocks x 256 threads; blocks 0..15 = fwd, 16..31 = bwd. WG owns 32 hidden units.
// Thread (rg=tid>>4, ks=tid&15): gate rows for units 2rg,2rg+1 over k slice [32ks,32ks+32).
// Cross-WG h exchange: (f32 h | u32 step-tag) packed in one 8B relaxed atomic.
// Consumers poll the data itself -> no fences, no flags, no barriers anywhere.
__launch_bounds__(256, 1)
__global__ void lstm_kernel(const float* __restrict__ pre,
                            const float* __restrict__ w_hh_f, const float* __restrict__ w_hh_b,
                            const float* __restrict__ h0, const float* __restrict__ c0,
                            float* __restrict__ hs, unsigned long long* __restrict__ ring)
{
    const int dir = blockIdx.x >> 4;
    const int wg  = blockIdx.x & 15;
    const int tid = threadIdx.x;
    const int rg  = tid >> 4;
    const int ks  = tid & 15;
    const int lane = tid & 63;
    const int wv   = tid >> 6;
    const float* w_hh = dir ? w_hh_b : w_hh_f;

    __shared__ float h_sh[4][576];   // wave-private padded h buffers (+4 per 32)
    float* hb = h_sh[wv];

    // one-time: weights into registers. row rl = rg*8+r -> grow=(rl&3)*512 + wg*32 + (rl>>2)
    float w[8][32];
    #pragma unroll
    for (int r = 0; r < 8; ++r) {
        int rl = rg * 8 + r;
        int grow = (rl & 3) * 512 + wg * 32 + (rl >> 2);
        const float4* src = (const float4*)(w_hh + (size_t)grow * 512 + ks * 32);
        #pragma unroll
        for (int q = 0; q < 8; ++q) {
            float4 v = src[q];
            w[r][q*4+0] = v.x; w[r][q*4+1] = v.y; w[r][q*4+2] = v.z; w[r][q*4+3] = v.w;
        }
    }

    // c-state: ks==0 lane of group rg owns hidden units j = wg*32 + 2rg, +1
    float c_a = 0.f, c_b = 0.f;
    if (ks == 0) {
        c_a = c0[dir * 512 + wg * 32 + 2 * rg];
        c_b = c0[dir * 512 + wg * 32 + 2 * rg + 1];
    }

    unsigned long long* ring_d = ring + dir * 1024;

    // prefetch pre for step 0: pf[r] = pre row gate=(r&3), unit 2rg+(r>>2)
    float pf[8];
    {
        int p0 = dir ? (S_LEN - 1) : 0;
        if (ks == 0) {
            const float* pb = pre + (size_t)p0 * 4096 + dir * 2048 + wg * 32 + 2 * rg;
            #pragma unroll
            for (int g = 0; g < 4; ++g) {
                float2 v = *(const float2*)(pb + g * 512);
                pf[g] = v.x; pf[4 + g] = v.y;
            }
        }
    }

    // stage h0 into this wave's buffer
    #pragma unroll
    for (int j = 0; j < 8; ++j) {
        int k = lane + 64 * j;
        hb[k + ((k >> 5) << 2)] = h0[dir * 512 + k];
    }

    for (int s = 0; s < S_LEN; ++s) {
        const int pos = dir ? (S_LEN - 1 - s) : s;

        if (s > 0) {   // poll prev-parity slot: all 512 tags must equal s
            unsigned long long* slot = ring_d + ((s - 1) & 1) * 512;
            const unsigned tgt = (unsigned)s;
            unsigned long long v[8];
            for (;;) {
                #pragma unroll
                for (int j = 0; j < 8; ++j)
                    v[j] = __hip_atomic_load(&slot[lane + 64 * j], __ATOMIC_RELAXED,
                                             __HIP_MEMORY_SCOPE_AGENT);
                bool ok = true;
                #pragma unroll
                for (int j = 0; j < 8; ++j) ok &= ((unsigned)(v[j] >> 32) == tgt);
                if (__all((int)ok)) break;
            }
            #pragma unroll
            for (int j = 0; j < 8; ++j) {
                int k = lane + 64 * j;
                hb[k + ((k >> 5) << 2)] = __uint_as_float((unsigned)(v[j] & 0xFFFFFFFFull));
            }
        }

        // gate pre-activations: 256 FMAs per thread over this thread's k-slice
        float acc[8] = {0, 0, 0, 0, 0, 0, 0, 0};
        const float4* hp = (const float4*)&hb[ks * 36];
        #pragma unroll
        for (int q = 0; q < 8; ++q) {
            float4 h4 = hp[q];
            #pragma unroll
            for (int r = 0; r < 8; ++r)
                acc[r] += w[r][q*4+0] * h4.x + w[r][q*4+1] * h4.y
                        + w[r][q*4+2] * h4.z + w[r][q*4+3] * h4.w;
        }
        if (ks == 0) {
            #pragma unroll
            for (int r = 0; r < 8; ++r) acc[r] += pf[r];
        }
        // butterfly all-reduce over the 16 k-slices (within 16-lane groups)
        #pragma unroll
        for (int m = 1; m <= 8; m <<= 1)
            #pragma unroll
            for (int r = 0; r < 8; ++r)
                acc[r] += __shfl_xor(acc[r], m);

        if (ks == 0) {
            float ia = sigm(acc[0]), fa = sigm(acc[1]), ga = tanhf(acc[2]), oa = sigm(acc[3]);
            c_a = fa * c_a + ia * ga;  float hn_a = oa * tanhf(c_a);
            float ib = sigm(acc[4]), fb = sigm(acc[5]), gb = tanhf(acc[6]), ob = sigm(acc[7]);
            c_b = fb * c_b + ib * gb;  float hn_b = ob * tanhf(c_b);

            const int j0 = wg * 32 + 2 * rg;
            const unsigned tag = (unsigned)(s + 1);
            unsigned long long pa = (unsigned long long)__float_as_uint(hn_a)
                                  | ((unsigned long long)tag << 32);
            unsigned long long pb = (unsigned long long)__float_as_uint(hn_b)
                                  | ((unsigned long long)tag << 32);
            unsigned long long* wslot = ring_d + (s & 1) * 512;
            __hip_atomic_store(&wslot[j0],     pa, __ATOMIC_RELAXED, __HIP_MEMORY_SCOPE_AGENT);
            __hip_atomic_store(&wslot[j0 + 1], pb, __ATOMIC_RELAXED, __HIP_MEMORY_SCOPE_AGENT);

            // off critical path: history store + next pre prefetch
            float* hsp = hs + ((size_t)dir * S_LEN + pos) * 512 + j0;
            __builtin_nontemporal_store(hn_a, &hsp[0]);
            __builtin_nontemporal_store(hn_b, &hsp[1]);
            if (s + 1 < S_LEN) {
                int pn = dir ? (pos - 1) : (pos + 1);
                const float* pb2 = pre + (size_t)pn * 4096 + dir * 2048 + wg * 32 + 2 * rg;
                #pragma unroll
                for (int g = 0; g < 4; ++g) {
                    float2 v = *(const float2*)(pb2 + g * 512);
                    pf[g] = v.x; pf[4 + g] = v.y;
                }
            }
        }
    }
}

// ---------------- kernel C: feats = concat(hf,hb) @ w_out^T + b_out ----------------
__launch_bounds__(256)
__global__ void feats_kernel(const float* __restrict__ hs, const float* __restrict__ w_out,
                             const float* __restrict__ b_out, float* __restrict__ feats)
{
    const int pos = blockIdx.x;
    const int tid = threadIdx.x;
    __shared__ float hbuf[1024];
    __shared__ float red[160];
    {
        const float* hf = hs + (size_t)pos * 512;
        const float* hb = hs + ((size_t)S_LEN + pos) * 512;
        if (tid < 128) *(float4*)&hbuf[tid * 4]        = *(const float4*)&hf[tid * 4];
        else           *(float4*)&hbuf[512 + (tid-128)*4] = *(const float4*)&hb[(tid - 128) * 4];
    }
    __syncthreads();
    if (tid < 160) {
        int tag = tid >> 3, part = tid & 7;
        const float* wrow = w_out + (size_t)tag * 1024 + part * 128;
        const float* hrow = hbuf + part * 128;
        float sum = 0.f;
        #pragma unroll
        for (int q = 0; q < 32; ++q) {
            float4 a = ((const float4*)hrow)[q];
            float4 b = ((const float4*)wrow)[q];
            sum += a.x*b.x + a.y*b.y + a.z*b.z + a.w*b.w;
        }
        red[tid] = sum;
    }
    __syncthreads();
    if (tid < NTAG) {
        float sum = b_out[tid];
        #pragma unroll
        for (int p = 0; p < 8; ++p) sum += red[tid * 8 + p];
        feats[(size_t)pos * NTAG + tid] = sum;
    }
}

// ---------------- kernel D: Viterbi forward + chunked backtrace ----------------
__launch_bounds__(256)
__global__ void viterbi_kernel(const float* __restrict__ feats, const float* __restrict__ trans,
                               unsigned char* __restrict__ bptr, float* __restrict__ out)
{
    __shared__ float feat_lds[64 * NTAG];
    __shared__ int sh_best;
    __shared__ unsigned char Mmap[8][NTAG];
    __shared__ unsigned char entry_s[8];
    const int tid = threadIdx.x;

    if (tid < 64) {   // wave 0: sequential forward pass
        const int lane = tid;
        const int i = (lane < NTAG) ? lane : (NTAG - 1);
        float trow[NTAG];
        #pragma unroll
        for (int j = 0; j < NTAG; ++j) trow[j] = trans[i * NTAG + j];
        float fv[NTAG];
        #pragma unroll
        for (int j = 0; j < NTAG; ++j) fv[j] = (j == 18) ? 0.f : NEGV;

        for (int blk = 0; blk < 64; ++blk) {
            #pragma unroll
            for (int q = 0; q < 20; ++q)
                feat_lds[q * 64 + lane] = feats[blk * 1280 + q * 64 + lane];
            for (int ss = 0; ss < 64; ++ss) {
                int s = blk * 64 + ss;
                float best = fv[0] + trow[0];
                int bj = 0;
                #pragma unroll
                for (int j = 1; j < NTAG; ++j) {
                    float cand = fv[j] + trow[j];
                    if (cand > best) { best = cand; bj = j; }   // strict >: first-max tie rule
                }
                float fnew = best + feat_lds[ss * NTAG + i];
                if (lane < NTAG) bptr[s * NTAG + lane] = (unsigned char)bj;
                #pragma unroll
                for (int j = 0; j < NTAG; ++j) fv[j] = __shfl(fnew, j);
            }
        }
        if (lane == 0) {
            float best = -1e30f; int bt = 0;
            for (int j = 0; j < NTAG; ++j) {
                float t2 = fv[j] + trans[TAG_STOP * NTAG + j];
                if (t2 > best) { best = t2; bt = j; }
            }
            out[0] = best;
            sh_best = bt;
        }
    }
    __syncthreads();
    // phase 1: per-chunk entry-tag -> chunk-start-tag maps (8 chunks x 20 entries)
    if (tid < 160) {
        int c = tid / NTAG, e = tid % NTAG;
        int tag = e;
        for (int t = (c + 1) * 512 - 1; t >= c * 512; --t) tag = bptr[t * NTAG + tag];
        Mmap[c][e] = (unsigned char)tag;
    }
    __syncthreads();
    // phase 2: serial chain through 8 chunk maps
    if (tid == 0) {
        int e = sh_best;
        entry_s[7] = (unsigned char)e;
        for (int c = 7; c >= 1; --c) { e = Mmap[c][e]; entry_s[c - 1] = (unsigned char)e; }
    }
    __syncthreads();
    // phase 3: re-walk each chunk writing the path
    if (tid < 8) {
        int c = tid;
        int tag = entry_s[c];
        out[1 + (c + 1) * 512 - 1] = (float)tag;
        for (int t = (c + 1) * 512 - 1; t > c * 512; --t) {
            tag = bptr[t * NTAG + tag];
            out[1 + t - 1] = (float)tag;
        }
    }
}

extern "C" void kernel_launch(void* const* d_in, const int* in_sizes, int n_in,
                              void* d_out, int out_size, void* d_ws, size_t ws_size,
                              hipStream_t stream) {
    (void)in_sizes; (void)n_in; (void)out_size; (void)ws_size;
    const int*   sent  = (const int*)d_in[0];
    const float* embed = (const float*)d_in[1];
    const float* wihf  = (const float*)d_in[2];
    const float* whhf  = (const float*)d_in[3];
    const float* bihf  = (const float*)d_in[4];
    const float* bhhf  = (const float*)d_in[5];
    const float* wihb  = (const float*)d_in[6];
    const float* whhb  = (const float*)d_in[7];
    const float* bihb  = (const float*)d_in[8];
    const float* bhhb  = (const float*)d_in[9];
    const float* wout  = (const float*)d_in[10];
    const float* bout  = (const float*)d_in[11];
    const float* trans = (const float*)d_in[12];
    const float* h0    = (const float*)d_in[13];
    const float* c0    = (const float*)d_in[14];

    char* ws = (char*)d_ws;
    unsigned long long* ring = (unsigned long long*)ws;   // 16 KB
    float* pre   = (float*)(ws + 16384);
    float* hs    = (float*)(ws + 16384 + (size_t)4096 * 4096 * 4);
    float* feats = (float*)(ws + 16384 + (size_t)4096 * 4096 * 4 + (size_t)2 * 4096 * 512 * 4);
    unsigned char* bptr = (unsigned char*)(feats + (size_t)S_LEN * NTAG);
    float* out = (float*)d_out;

    hipLaunchKernelGGL(pre_gemm, dim3(2048), dim3(256), 0, stream,
                       sent, embed, wihf, wihb, bihf, bhhf, bihb, bhhb, pre);
    hipLaunchKernelGGL(lstm_kernel, dim3(32), dim3(256), 0, stream,
                       pre, whhf, whhb, h0, c0, hs, ring);
    hipLaunchKernelGGL(feats_kernel, dim3(S_LEN), dim3(256), 0, stream,
                       hs, wout, bout, feats);
    hipLaunchKernelGGL(viterbi_kernel, dim3(1), dim3(256), 0, stream,
                       feats, trans, bptr, out);
}